// Round 4
// baseline (295.993 us; speedup 1.0000x reference)
//
#include <hip/hip_runtime.h>
#include <hip/hip_fp16.h>

#define D 64
#define NEG_SLOPE 0.01f
#define CB_SHIFT 9           // 512 nodes per coarse bucket
#define CB_NODES 512
#define MAXCB 256            // supports N <= 131072
#define CHUNK 4096           // edges per scatter block
#define BCAP 10240           // fixed bucket slab capacity (mean 8163, +23 sigma)
#define SADJ_CAP 10240       // LDS adj stage (40 KB)
#define CGRID 256            // convert blocks fused behind scatter
#define SAH 72               // mh LDS row stride (halves): 144 B -> 2-way alias only

typedef _Float16 f16x8 __attribute__((ext_vector_type(8)));
typedef float    f32x4 __attribute__((ext_vector_type(4)));

// ---------------------------------------------------------------------------
// Scatter workspace (24.6 KB) — 6 blocks/CU.
// ---------------------------------------------------------------------------
struct ScatSmem {
    int hist[MAXCB];
    int lofs[MAXCB];
    int gbase[MAXCB];
    int cur[MAXCB];
    int swsum[4];
    unsigned spk[CHUNK];          // 16 KB
    unsigned char sbk[CHUNK];     // 4 KB
};

__device__ __forceinline__ int detect64(const void* __restrict__ ei) {
    int lane = threadIdx.x & 63;
    int v = ((const int*)ei)[2 * lane + 1];
    return (__ballot(v != 0) == 0ULL) ? 1 : 0;
}

__device__ __forceinline__ int edge_at(const void* __restrict__ ei, long long idx, int is64) {
    if (is64) return (int)((const long long*)ei)[idx];
    return ((const int*)ei)[idx];
}

// ---------------------------------------------------------------------------
// Coarse scatter body (R12-proven).
// ---------------------------------------------------------------------------
__device__ __forceinline__ void scatter_body(ScatSmem& sm,
        const void* __restrict__ ei, long long E,
        int* __restrict__ bcursor, unsigned* __restrict__ ebuf,
        int ncb, int bid) {
    int t = threadIdx.x;
    sm.hist[t] = 0;
    int is64 = detect64(ei);
    __syncthreads();
    long long start = (long long)bid * CHUNK;
    int ccnt = (int)min((long long)CHUNK, E - start);

    for (int i = t; i < ccnt; i += 256) {
        int d = edge_at(ei, E + start + i, is64);
        atomicAdd(&sm.hist[d >> CB_SHIFT], 1);
    }
    __syncthreads();
    {   // block exclusive scan of hist[256] -> lofs
        int v = sm.hist[t];
        int lane = t & 63, w = t >> 6;
        int inc = v;
        for (int off = 1; off < 64; off <<= 1) {
            int u = __shfl_up(inc, off, 64);
            if (lane >= off) inc += u;
        }
        if (lane == 63) sm.swsum[w] = inc;
        __syncthreads();
        int wof = 0;
        for (int i = 0; i < w; ++i) wof += sm.swsum[i];
        sm.lofs[t] = wof + inc - v;
    }
    if (t < ncb && sm.hist[t]) sm.gbase[t] = atomicAdd(&bcursor[t], sm.hist[t]);
    __syncthreads();
    sm.cur[t] = sm.lofs[t];
    __syncthreads();

    for (int i = t; i < ccnt; i += 256) {
        int s = edge_at(ei, start + i, is64);
        int d = edge_at(ei, E + start + i, is64);
        int b = d >> CB_SHIFT;
        int slot = atomicAdd(&sm.cur[b], 1);
        sm.spk[slot] = ((unsigned)s << CB_SHIFT) | (unsigned)(d & (CB_NODES - 1));
        sm.sbk[slot] = (unsigned char)b;
    }
    __syncthreads();

    for (int i = t; i < ccnt; i += 256) {
        int b = sm.sbk[i];
        int dst = sm.gbase[b] + (i - sm.lofs[b]);
        if (dst < BCAP) ebuf[(size_t)b * BCAP + dst] = sm.spk[i];
    }
}

// ---------------------------------------------------------------------------
// Convert role: x fp32 -> fp16 and the six 64x64 weights -> fp16.
// ---------------------------------------------------------------------------
__device__ __forceinline__ void conv_body(const float* __restrict__ x,
        _Float16* __restrict__ x16, long long U, int cid,
        const float* __restrict__ Wl1, const float* __restrict__ Wr1,
        const float* __restrict__ Wl2, const float* __restrict__ Wr2,
        const float* __restrict__ Wl3, const float* __restrict__ Wr3,
        _Float16* __restrict__ W16) {
    int t = threadIdx.x;
    for (long long u = (long long)cid * 256 + t; u < U; u += (long long)CGRID * 256) {
        const float* s = x + u * 8;
        const float4 v0 = *(const float4*)s;
        const float4 v1 = *(const float4*)(s + 4);
        f16x8 o = { (_Float16)v0.x, (_Float16)v0.y, (_Float16)v0.z, (_Float16)v0.w,
                    (_Float16)v1.x, (_Float16)v1.y, (_Float16)v1.z, (_Float16)v1.w };
        *(f16x8*)(x16 + u * 8) = o;
    }
    if (cid == 0) {
        const float* Ws[6] = { Wl1, Wr1, Wl2, Wr2, Wl3, Wr3 };
#pragma unroll
        for (int m = 0; m < 6; ++m) {
            const float* src = Ws[m];
            _Float16* dst = W16 + m * 4096;
            for (int i = t; i < 4096; i += 256) dst[i] = (_Float16)src[i];
        }
    }
}

__global__ __launch_bounds__(256, 6) void scatter_conv_kernel(
        const void* __restrict__ ei, long long E,
        int* __restrict__ bcursor, unsigned* __restrict__ ebuf, int ncb, int sgrid,
        const float* __restrict__ x, _Float16* __restrict__ x16, long long U,
        const float* __restrict__ Wl1, const float* __restrict__ Wr1,
        const float* __restrict__ Wl2, const float* __restrict__ Wr2,
        const float* __restrict__ Wl3, const float* __restrict__ Wr3,
        _Float16* __restrict__ W16) {
    __shared__ ScatSmem sm;
    if ((int)blockIdx.x < sgrid)
        scatter_body(sm, ei, E, bcursor, ebuf, ncb, blockIdx.x);
    else
        conv_body(x, x16, U, blockIdx.x - sgrid, Wl1, Wr1, Wl2, Wr2, Wl3, Wr3, W16);
}

// ---------------------------------------------------------------------------
// FUSED agg + gemm, now 512 threads (8 waves) per 128-node tile:
//   phase A: 64 groups x 8 lanes gather mean_j h_j (2 passes), unroll-8
//            edge batches (2x MLP vs R3) -> LDS mh tile [128][SAH] fp16.
//   phase B: 8 waves, each one 16-row M-tile: h_next = leaky(mh@Wl^T +
//            h@Wr^T + bl), 16 MFMAs/wave. mh A-frags from LDS, h from global.
// 512t blocks double waves/CU during the latency-bound gather (12 -> 24).
// final_flag: fuse head out = h4 @ Wout^T + bout (16-lane shfl reduce).
// ---------------------------------------------------------------------------
__global__ __launch_bounds__(512) void agg_gemm_kernel(
        const _Float16* __restrict__ Hin,
        const int* __restrict__ rowptr, const int* __restrict__ adj,
        const _Float16* __restrict__ W16,      // Wl at 0, Wr at +4096
        const float* __restrict__ bl,
        _Float16* __restrict__ Hout,
        const float* __restrict__ Wout, const float* __restrict__ bout,
        float* __restrict__ out, int N, int final_flag) {
    __shared__ _Float16 smh[128 * SAH];        // 18432 B
    int t = threadIdx.x;
    int node_base = (int)blockIdx.x * 128;

    // ---- phase A: gather means ----
    {
        int g = t >> 3;            // group 0..63
        int sub = t & 7;           // 16 B channel slot
        size_t cofs = (size_t)(sub << 3);
#pragma unroll
        for (int p = 0; p < 2; ++p) {
            int local = p * 64 + g;
            int i = node_base + local;
            float a0 = 0.f, a1 = 0.f, a2 = 0.f, a3 = 0.f;
            float a4 = 0.f, a5 = 0.f, a6 = 0.f, a7 = 0.f;
            float inv = 0.f;
            if (i < N) {
                int b0 = rowptr[i], b1 = rowptr[i + 1];
                int e = b0;
                int nfull = (b1 - b0) >> 3;
                for (int q = 0; q < nfull; ++q) {
                    int s0 = adj[e], s1 = adj[e + 1], s2 = adj[e + 2], s3 = adj[e + 3];
                    int s4 = adj[e + 4], s5 = adj[e + 5], s6 = adj[e + 6], s7 = adj[e + 7];
                    e += 8;
                    union { float4 f4; __half2 h2[4]; } u0, u1, u2, u3, u4, u5, u6, u7;
                    u0.f4 = *(const float4*)(Hin + (size_t)s0 * D + cofs);
                    u1.f4 = *(const float4*)(Hin + (size_t)s1 * D + cofs);
                    u2.f4 = *(const float4*)(Hin + (size_t)s2 * D + cofs);
                    u3.f4 = *(const float4*)(Hin + (size_t)s3 * D + cofs);
                    u4.f4 = *(const float4*)(Hin + (size_t)s4 * D + cofs);
                    u5.f4 = *(const float4*)(Hin + (size_t)s5 * D + cofs);
                    u6.f4 = *(const float4*)(Hin + (size_t)s6 * D + cofs);
                    u7.f4 = *(const float4*)(Hin + (size_t)s7 * D + cofs);
#define ACC8(u) { \
        float2 v0 = __half22float2(u.h2[0]); float2 v1 = __half22float2(u.h2[1]); \
        float2 v2 = __half22float2(u.h2[2]); float2 v3 = __half22float2(u.h2[3]); \
        a0 += v0.x; a1 += v0.y; a2 += v1.x; a3 += v1.y; \
        a4 += v2.x; a5 += v2.y; a6 += v3.x; a7 += v3.y; }
                    ACC8(u0) ACC8(u1) ACC8(u2) ACC8(u3)
                    ACC8(u4) ACC8(u5) ACC8(u6) ACC8(u7)
                }
                for (; e < b1; ++e) {
                    int s = adj[e];
                    union { float4 f4; __half2 h2[4]; } u;
                    u.f4 = *(const float4*)(Hin + (size_t)s * D + cofs);
                    ACC8(u)
                }
#undef ACC8
                inv = 1.0f / fmaxf((float)(b1 - b0), 1.0f);
            }
            f16x8 o = { (_Float16)(a0 * inv), (_Float16)(a1 * inv),
                        (_Float16)(a2 * inv), (_Float16)(a3 * inv),
                        (_Float16)(a4 * inv), (_Float16)(a5 * inv),
                        (_Float16)(a6 * inv), (_Float16)(a7 * inv) };
            *(f16x8*)(smh + local * SAH + (sub << 3)) = o;
        }
    }
    __syncthreads();

    // ---- phase B: MFMA gemm, wave w owns rows [w*16, w*16+16) ----
    int w = t >> 6, lane = t & 63;
    int lr = lane & 15;        // row-in-tile (A) / col-in-tile (B,D)
    int lk = lane >> 4;        // k-group / D row-group
    int rbase = node_base + w * 16;

    f16x8 ah[2], am[2];
    {
        int gn = rbase + lr;
        if (gn >= N) gn = N - 1;               // pad rows: garbage ok, masked later
        const _Float16* hp = Hin + (size_t)gn * D + lk * 8;
        ah[0] = *(const f16x8*)hp;  ah[1] = *(const f16x8*)(hp + 32);
        const _Float16* mp = smh + (w * 16 + lr) * SAH + lk * 8;
        am[0] = *(const f16x8*)mp;  am[1] = *(const f16x8*)(mp + 32);
    }

    f32x4 acc[4];
#pragma unroll
    for (int nt = 0; nt < 4; ++nt)
        acc[nt] = (f32x4){0.f, 0.f, 0.f, 0.f};

    const _Float16* Wl = W16;
    const _Float16* Wr = W16 + 4096;
#pragma unroll
    for (int nt = 0; nt < 4; ++nt) {
        const _Float16* pl = Wl + (nt * 16 + lr) * D + lk * 8;
        const _Float16* pr = Wr + (nt * 16 + lr) * D + lk * 8;
        f16x8 b0 = *(const f16x8*)pl;  f16x8 b1 = *(const f16x8*)(pl + 32);
        f16x8 c0 = *(const f16x8*)pr;  f16x8 c1 = *(const f16x8*)(pr + 32);
        acc[nt] = __builtin_amdgcn_mfma_f32_16x16x32_f16(am[0], b0, acc[nt], 0, 0, 0);
        acc[nt] = __builtin_amdgcn_mfma_f32_16x16x32_f16(am[1], b1, acc[nt], 0, 0, 0);
        acc[nt] = __builtin_amdgcn_mfma_f32_16x16x32_f16(ah[0], c0, acc[nt], 0, 0, 0);
        acc[nt] = __builtin_amdgcn_mfma_f32_16x16x32_f16(ah[1], c1, acc[nt], 0, 0, 0);
    }

    float blv[4];
#pragma unroll
    for (int nt = 0; nt < 4; ++nt) blv[nt] = bl[nt * 16 + lr];

    if (!final_flag) {
#pragma unroll
        for (int r = 0; r < 4; ++r) {
            int gn = rbase + lk * 4 + r;
            if (gn < N) {
#pragma unroll
                for (int nt = 0; nt < 4; ++nt) {
                    float y = acc[nt][r] + blv[nt];
                    y = (y >= 0.f) ? y : NEG_SLOPE * y;
                    Hout[(size_t)gn * D + nt * 16 + lr] = (_Float16)y;
                }
            }
        }
    } else {
        float wv[4];
#pragma unroll
        for (int nt = 0; nt < 4; ++nt) wv[nt] = Wout[nt * 16 + lr];
        float bo = bout[0];
#pragma unroll
        for (int r = 0; r < 4; ++r) {
            float p = 0.f;
#pragma unroll
            for (int nt = 0; nt < 4; ++nt) {
                float y = acc[nt][r] + blv[nt];
                y = (y >= 0.f) ? y : NEG_SLOPE * y;
                p += y * wv[nt];
            }
            p += __shfl_xor(p, 1, 64);   // reduce over the 16 lr lanes
            p += __shfl_xor(p, 2, 64);
            p += __shfl_xor(p, 4, 64);
            p += __shfl_xor(p, 8, 64);
            int gn = rbase + lk * 4 + r;
            if (lr == 0 && gn < N) out[gn] = p + bo;
        }
    }
}

// ---------------------------------------------------------------------------
// Fine fill (R12-proven, unchanged): one block per coarse bucket.
// ---------------------------------------------------------------------------
__global__ __launch_bounds__(256) void finefill_kernel(
        const unsigned* __restrict__ ebuf, const int* __restrict__ bcount,
        int* __restrict__ rowptr, int* __restrict__ adj, int N, int ncb) {
    __shared__ int cnt[CB_NODES];
    __shared__ int cur[CB_NODES];
    __shared__ int wpart[4];
    __shared__ int wsum4[4];
    __shared__ int se0;
    __shared__ int sAdj[SADJ_CAP];
    int t = threadIdx.x;
    int b = blockIdx.x;

    {
        int v = (t < ncb) ? min(bcount[t], BCAP) : 0;
        int lane = t & 63, w = t >> 6;
        int inc = v;
        for (int off = 1; off < 64; off <<= 1) {
            int u = __shfl_up(inc, off, 64);
            if (lane >= off) inc += u;
        }
        if (lane == 63) wsum4[w] = inc;
        __syncthreads();
        int wof = 0;
        for (int iw = 0; iw < w; ++iw) wof += wsum4[iw];
        int ex = wof + inc - v;
        if (t == b) se0 = ex;
        if (b == 0 && t == 0)
            rowptr[N] = wsum4[0] + wsum4[1] + wsum4[2] + wsum4[3];
    }
    __syncthreads();
    int e0 = se0;
    int len = min(bcount[b], BCAP);
    int nb = b << CB_SHIFT;
    const unsigned* slab = ebuf + (size_t)b * BCAP;

    cnt[2 * t] = 0; cnt[2 * t + 1] = 0;
    __syncthreads();
    for (int i = t; i < len; i += 256) {
        unsigned p = slab[i];
        atomicAdd(&cnt[p & (CB_NODES - 1)], 1);
    }
    __syncthreads();

    int c0 = cnt[2 * t], c1 = cnt[2 * t + 1];
    int s = c0 + c1;
    int lane = t & 63, wv = t >> 6;
    int inc = s;
    for (int off = 1; off < 64; off <<= 1) {
        int u = __shfl_up(inc, off, 64);
        if (lane >= off) inc += u;
    }
    if (lane == 63) wpart[wv] = inc;
    __syncthreads();
    int wof = 0;
    for (int w = 0; w < wv; ++w) wof += wpart[w];
    int ex = wof + inc - s;
    cur[2 * t] = ex; cur[2 * t + 1] = ex + c0;
    {
        int g = nb + 2 * t;
        if (g < N)     rowptr[g]     = e0 + ex;
        if (g + 1 < N) rowptr[g + 1] = e0 + ex + c0;
    }
    __syncthreads();

    int big = (len > SADJ_CAP);
    for (int i = t; i < len; i += 256) {
        unsigned p = slab[i];
        int dl = (int)(p & (CB_NODES - 1));
        int src = (int)(p >> CB_SHIFT);
        int pos = atomicAdd(&cur[dl], 1);
        if (big) adj[e0 + pos] = src;
        else     sAdj[pos] = src;
    }
    __syncthreads();
    if (!big) {
        for (int i = t; i < len; i += 256) adj[e0 + i] = sAdj[i];
    }
}

extern "C" void kernel_launch(void* const* d_in, const int* in_sizes, int n_in,
                              void* d_out, int out_size, void* d_ws, size_t ws_size,
                              hipStream_t stream) {
    const float* x    = (const float*)d_in[0];
    const void*  ei   = d_in[1];
    const float* Wl1  = (const float*)d_in[2];
    const float* bl1  = (const float*)d_in[3];
    const float* Wr1  = (const float*)d_in[4];
    const float* Wl2  = (const float*)d_in[5];
    const float* bl2  = (const float*)d_in[6];
    const float* Wr2  = (const float*)d_in[7];
    const float* Wl3  = (const float*)d_in[8];
    const float* bl3  = (const float*)d_in[9];
    const float* Wr3  = (const float*)d_in[10];
    const float* Wout = (const float*)d_in[11];
    const float* bout = (const float*)d_in[12];
    float* out = (float*)d_out;

    int       N = in_sizes[0] / D;
    long long E = (long long)in_sizes[1] / 2;
    int ncb = (N + CB_NODES - 1) >> CB_SHIFT;   // <= 256 for N <= 131072
    long long U = (long long)N * D / 8;         // float8 convert units

    // workspace layout
    char* ws = (char*)d_ws;
    size_t off = 256;
    int* bcursor = (int*)(ws + off); off += 1024;   // 256 ints
    int* rowptr = (int*)(ws + off); off += (((size_t)(N + 1) * 4 + 255) / 256) * 256;
    int* adj    = (int*)(ws + off); off += (((size_t)E * 4 + 255) / 256) * 256;
    unsigned* ebuf = (unsigned*)(ws + off); off += (size_t)ncb * BCAP * 4;
    _Float16* x16 = (_Float16*)(ws + off); off += (size_t)N * D * 2;
    _Float16* hA  = (_Float16*)(ws + off); off += (size_t)N * D * 2;
    _Float16* hB  = (_Float16*)(ws + off); off += (size_t)N * D * 2;
    _Float16* W16 = (_Float16*)(ws + off); off += 6 * 4096 * 2;

    int sgrid = (int)((E + CHUNK - 1) / CHUNK);
    int ggrid = (N + 127) / 128;

    hipMemsetAsync(bcursor, 0, 1024, stream);

    // K1: CSR scatter runs concurrently with fp16 conversion of x and weights
    scatter_conv_kernel<<<sgrid + CGRID, 256, 0, stream>>>(
        ei, E, bcursor, ebuf, ncb, sgrid,
        x, x16, U, Wl1, Wr1, Wl2, Wr2, Wl3, Wr3, W16);
    finefill_kernel<<<ncb, 256, 0, stream>>>(ebuf, bcursor, rowptr, adj, N, ncb);
    // ---- layer 1 (fused agg+gemm) ----
    agg_gemm_kernel<<<ggrid, 512, 0, stream>>>(x16, rowptr, adj, W16, bl1, hA,
                                               Wout, bout, out, N, 0);
    // ---- layer 2 ----
    agg_gemm_kernel<<<ggrid, 512, 0, stream>>>(hA, rowptr, adj, W16 + 2 * 4096, bl2, hB,
                                               Wout, bout, out, N, 0);
    // ---- layer 3 + fused head (h4 never materialized) ----
    agg_gemm_kernel<<<ggrid, 512, 0, stream>>>(hB, rowptr, adj, W16 + 4 * 4096, bl3, hA,
                                               Wout, bout, out, N, 1);
}

// Round 5
// 260.438 us; speedup vs baseline: 1.1365x; 1.1365x over previous
//
#include <hip/hip_runtime.h>
#include <hip/hip_fp16.h>

#define D 64
#define NEG_SLOPE 0.01f
#define CB_SHIFT 9           // 512 nodes per coarse bucket
#define CB_NODES 512
#define MAXCB 256            // supports N <= 131072
#define CHUNK 4096           // edges per scatter block
#define BCAP 10240           // fixed bucket slab capacity (mean 8163, +23 sigma)
#define SADJ_CAP 10240       // LDS adj stage (40 KB)
#define CGRID 256            // convert blocks fused behind scatter
#define SAH 72               // mh LDS row stride (halves): 144 B -> 2-way alias only
#define TILE 64              // nodes per agg_gemm block (R5: halved for 2x blocks)

typedef _Float16 f16x8 __attribute__((ext_vector_type(8)));
typedef float    f32x4 __attribute__((ext_vector_type(4)));

// ---------------------------------------------------------------------------
// Scatter workspace (24.6 KB) — 6 blocks/CU.
// ---------------------------------------------------------------------------
struct ScatSmem {
    int hist[MAXCB];
    int lofs[MAXCB];
    int gbase[MAXCB];
    int cur[MAXCB];
    int swsum[4];
    unsigned spk[CHUNK];          // 16 KB
    unsigned char sbk[CHUNK];     // 4 KB
};

__device__ __forceinline__ int detect64(const void* __restrict__ ei) {
    int lane = threadIdx.x & 63;
    int v = ((const int*)ei)[2 * lane + 1];
    return (__ballot(v != 0) == 0ULL) ? 1 : 0;
}

__device__ __forceinline__ int edge_at(const void* __restrict__ ei, long long idx, int is64) {
    if (is64) return (int)((const long long*)ei)[idx];
    return ((const int*)ei)[idx];
}

// ---------------------------------------------------------------------------
// Coarse scatter body (R12-proven).
// ---------------------------------------------------------------------------
__device__ __forceinline__ void scatter_body(ScatSmem& sm,
        const void* __restrict__ ei, long long E,
        int* __restrict__ bcursor, unsigned* __restrict__ ebuf,
        int ncb, int bid) {
    int t = threadIdx.x;
    sm.hist[t] = 0;
    int is64 = detect64(ei);
    __syncthreads();
    long long start = (long long)bid * CHUNK;
    int ccnt = (int)min((long long)CHUNK, E - start);

    for (int i = t; i < ccnt; i += 256) {
        int d = edge_at(ei, E + start + i, is64);
        atomicAdd(&sm.hist[d >> CB_SHIFT], 1);
    }
    __syncthreads();
    {   // block exclusive scan of hist[256] -> lofs
        int v = sm.hist[t];
        int lane = t & 63, w = t >> 6;
        int inc = v;
        for (int off = 1; off < 64; off <<= 1) {
            int u = __shfl_up(inc, off, 64);
            if (lane >= off) inc += u;
        }
        if (lane == 63) sm.swsum[w] = inc;
        __syncthreads();
        int wof = 0;
        for (int i = 0; i < w; ++i) wof += sm.swsum[i];
        sm.lofs[t] = wof + inc - v;
    }
    if (t < ncb && sm.hist[t]) sm.gbase[t] = atomicAdd(&bcursor[t], sm.hist[t]);
    __syncthreads();
    sm.cur[t] = sm.lofs[t];
    __syncthreads();

    for (int i = t; i < ccnt; i += 256) {
        int s = edge_at(ei, start + i, is64);
        int d = edge_at(ei, E + start + i, is64);
        int b = d >> CB_SHIFT;
        int slot = atomicAdd(&sm.cur[b], 1);
        sm.spk[slot] = ((unsigned)s << CB_SHIFT) | (unsigned)(d & (CB_NODES - 1));
        sm.sbk[slot] = (unsigned char)b;
    }
    __syncthreads();

    for (int i = t; i < ccnt; i += 256) {
        int b = sm.sbk[i];
        int dst = sm.gbase[b] + (i - sm.lofs[b]);
        if (dst < BCAP) ebuf[(size_t)b * BCAP + dst] = sm.spk[i];
    }
}

// ---------------------------------------------------------------------------
// Convert role: x fp32 -> fp16 and the six 64x64 weights -> fp16.
// ---------------------------------------------------------------------------
__device__ __forceinline__ void conv_body(const float* __restrict__ x,
        _Float16* __restrict__ x16, long long U, int cid,
        const float* __restrict__ Wl1, const float* __restrict__ Wr1,
        const float* __restrict__ Wl2, const float* __restrict__ Wr2,
        const float* __restrict__ Wl3, const float* __restrict__ Wr3,
        _Float16* __restrict__ W16) {
    int t = threadIdx.x;
    for (long long u = (long long)cid * 256 + t; u < U; u += (long long)CGRID * 256) {
        const float* s = x + u * 8;
        const float4 v0 = *(const float4*)s;
        const float4 v1 = *(const float4*)(s + 4);
        f16x8 o = { (_Float16)v0.x, (_Float16)v0.y, (_Float16)v0.z, (_Float16)v0.w,
                    (_Float16)v1.x, (_Float16)v1.y, (_Float16)v1.z, (_Float16)v1.w };
        *(f16x8*)(x16 + u * 8) = o;
    }
    if (cid == 0) {
        const float* Ws[6] = { Wl1, Wr1, Wl2, Wr2, Wl3, Wr3 };
#pragma unroll
        for (int m = 0; m < 6; ++m) {
            const float* src = Ws[m];
            _Float16* dst = W16 + m * 4096;
            for (int i = t; i < 4096; i += 256) dst[i] = (_Float16)src[i];
        }
    }
}

__global__ __launch_bounds__(256, 6) void scatter_conv_kernel(
        const void* __restrict__ ei, long long E,
        int* __restrict__ bcursor, unsigned* __restrict__ ebuf, int ncb, int sgrid,
        const float* __restrict__ x, _Float16* __restrict__ x16, long long U,
        const float* __restrict__ Wl1, const float* __restrict__ Wr1,
        const float* __restrict__ Wl2, const float* __restrict__ Wr2,
        const float* __restrict__ Wl3, const float* __restrict__ Wr3,
        _Float16* __restrict__ W16) {
    __shared__ ScatSmem sm;
    if ((int)blockIdx.x < sgrid)
        scatter_body(sm, ei, E, bcursor, ebuf, ncb, blockIdx.x);
    else
        conv_body(x, x16, U, blockIdx.x - sgrid, Wl1, Wr1, Wl2, Wr2, Wl3, Wr3, W16);
}

// ---------------------------------------------------------------------------
// FUSED agg + gemm, 64-node tile, 256 threads (R3 structure, 2x grid):
//   phase A: 32 groups x 8 lanes gather mean_j h_j (2 passes), unroll-4
//            edge batches -> LDS mh tile [64][SAH] fp16.
//   phase B: 4 waves, each one 16-row M-tile: h_next = leaky(mh@Wl^T +
//            h@Wr^T + bl), 16 MFMAs/wave. mh A-frags from LDS, h from global.
// Grid 1563 blocks -> ~6.1 blocks/CU -> ~24 waves/CU ceiling (was ~12).
// final_flag: fuse head out = h4 @ Wout^T + bout (16-lane shfl reduce).
// ---------------------------------------------------------------------------
__global__ __launch_bounds__(256) void agg_gemm_kernel(
        const _Float16* __restrict__ Hin,
        const int* __restrict__ rowptr, const int* __restrict__ adj,
        const _Float16* __restrict__ W16,      // Wl at 0, Wr at +4096
        const float* __restrict__ bl,
        _Float16* __restrict__ Hout,
        const float* __restrict__ Wout, const float* __restrict__ bout,
        float* __restrict__ out, int N, int final_flag) {
    __shared__ _Float16 smh[TILE * SAH];       // 9216 B
    int t = threadIdx.x;
    int node_base = (int)blockIdx.x * TILE;

    // ---- phase A: gather means ----
    {
        int g = t >> 3;            // group 0..31
        int sub = t & 7;           // 16 B channel slot
        size_t cofs = (size_t)(sub << 3);
#pragma unroll
        for (int p = 0; p < 2; ++p) {
            int local = p * 32 + g;
            int i = node_base + local;
            float a0 = 0.f, a1 = 0.f, a2 = 0.f, a3 = 0.f;
            float a4 = 0.f, a5 = 0.f, a6 = 0.f, a7 = 0.f;
            float inv = 0.f;
            if (i < N) {
                int b0 = rowptr[i], b1 = rowptr[i + 1];
                int e = b0;
                int nfull = (b1 - b0) >> 2;
                for (int q = 0; q < nfull; ++q) {
                    int s0 = adj[e], s1 = adj[e + 1], s2 = adj[e + 2], s3 = adj[e + 3];
                    e += 4;
                    union { float4 f4; __half2 h2[4]; } u0, u1, u2, u3;
                    u0.f4 = *(const float4*)(Hin + (size_t)s0 * D + cofs);
                    u1.f4 = *(const float4*)(Hin + (size_t)s1 * D + cofs);
                    u2.f4 = *(const float4*)(Hin + (size_t)s2 * D + cofs);
                    u3.f4 = *(const float4*)(Hin + (size_t)s3 * D + cofs);
#define ACC8(u) { \
        float2 v0 = __half22float2(u.h2[0]); float2 v1 = __half22float2(u.h2[1]); \
        float2 v2 = __half22float2(u.h2[2]); float2 v3 = __half22float2(u.h2[3]); \
        a0 += v0.x; a1 += v0.y; a2 += v1.x; a3 += v1.y; \
        a4 += v2.x; a5 += v2.y; a6 += v3.x; a7 += v3.y; }
                    ACC8(u0) ACC8(u1) ACC8(u2) ACC8(u3)
                }
                for (; e < b1; ++e) {
                    int s = adj[e];
                    union { float4 f4; __half2 h2[4]; } u;
                    u.f4 = *(const float4*)(Hin + (size_t)s * D + cofs);
                    ACC8(u)
                }
#undef ACC8
                inv = 1.0f / fmaxf((float)(b1 - b0), 1.0f);
            }
            f16x8 o = { (_Float16)(a0 * inv), (_Float16)(a1 * inv),
                        (_Float16)(a2 * inv), (_Float16)(a3 * inv),
                        (_Float16)(a4 * inv), (_Float16)(a5 * inv),
                        (_Float16)(a6 * inv), (_Float16)(a7 * inv) };
            *(f16x8*)(smh + local * SAH + (sub << 3)) = o;
        }
    }
    __syncthreads();

    // ---- phase B: MFMA gemm, wave w owns rows [w*16, w*16+16) ----
    int w = t >> 6, lane = t & 63;
    int lr = lane & 15;        // row-in-tile (A) / col-in-tile (B,D)
    int lk = lane >> 4;        // k-group / D row-group
    int rbase = node_base + w * 16;

    f16x8 ah[2], am[2];
    {
        int gn = rbase + lr;
        if (gn >= N) gn = N - 1;               // pad rows: garbage ok, masked later
        const _Float16* hp = Hin + (size_t)gn * D + lk * 8;
        ah[0] = *(const f16x8*)hp;  ah[1] = *(const f16x8*)(hp + 32);
        const _Float16* mp = smh + (w * 16 + lr) * SAH + lk * 8;
        am[0] = *(const f16x8*)mp;  am[1] = *(const f16x8*)(mp + 32);
    }

    f32x4 acc[4];
#pragma unroll
    for (int nt = 0; nt < 4; ++nt)
        acc[nt] = (f32x4){0.f, 0.f, 0.f, 0.f};

    const _Float16* Wl = W16;
    const _Float16* Wr = W16 + 4096;
#pragma unroll
    for (int nt = 0; nt < 4; ++nt) {
        const _Float16* pl = Wl + (nt * 16 + lr) * D + lk * 8;
        const _Float16* pr = Wr + (nt * 16 + lr) * D + lk * 8;
        f16x8 b0 = *(const f16x8*)pl;  f16x8 b1 = *(const f16x8*)(pl + 32);
        f16x8 c0 = *(const f16x8*)pr;  f16x8 c1 = *(const f16x8*)(pr + 32);
        acc[nt] = __builtin_amdgcn_mfma_f32_16x16x32_f16(am[0], b0, acc[nt], 0, 0, 0);
        acc[nt] = __builtin_amdgcn_mfma_f32_16x16x32_f16(am[1], b1, acc[nt], 0, 0, 0);
        acc[nt] = __builtin_amdgcn_mfma_f32_16x16x32_f16(ah[0], c0, acc[nt], 0, 0, 0);
        acc[nt] = __builtin_amdgcn_mfma_f32_16x16x32_f16(ah[1], c1, acc[nt], 0, 0, 0);
    }

    float blv[4];
#pragma unroll
    for (int nt = 0; nt < 4; ++nt) blv[nt] = bl[nt * 16 + lr];

    if (!final_flag) {
#pragma unroll
        for (int r = 0; r < 4; ++r) {
            int gn = rbase + lk * 4 + r;
            if (gn < N) {
#pragma unroll
                for (int nt = 0; nt < 4; ++nt) {
                    float y = acc[nt][r] + blv[nt];
                    y = (y >= 0.f) ? y : NEG_SLOPE * y;
                    Hout[(size_t)gn * D + nt * 16 + lr] = (_Float16)y;
                }
            }
        }
    } else {
        float wv[4];
#pragma unroll
        for (int nt = 0; nt < 4; ++nt) wv[nt] = Wout[nt * 16 + lr];
        float bo = bout[0];
#pragma unroll
        for (int r = 0; r < 4; ++r) {
            float p = 0.f;
#pragma unroll
            for (int nt = 0; nt < 4; ++nt) {
                float y = acc[nt][r] + blv[nt];
                y = (y >= 0.f) ? y : NEG_SLOPE * y;
                p += y * wv[nt];
            }
            p += __shfl_xor(p, 1, 64);   // reduce over the 16 lr lanes
            p += __shfl_xor(p, 2, 64);
            p += __shfl_xor(p, 4, 64);
            p += __shfl_xor(p, 8, 64);
            int gn = rbase + lk * 4 + r;
            if (lr == 0 && gn < N) out[gn] = p + bo;
        }
    }
}

// ---------------------------------------------------------------------------
// Fine fill (R12-proven, unchanged): one block per coarse bucket.
// ---------------------------------------------------------------------------
__global__ __launch_bounds__(256) void finefill_kernel(
        const unsigned* __restrict__ ebuf, const int* __restrict__ bcount,
        int* __restrict__ rowptr, int* __restrict__ adj, int N, int ncb) {
    __shared__ int cnt[CB_NODES];
    __shared__ int cur[CB_NODES];
    __shared__ int wpart[4];
    __shared__ int wsum4[4];
    __shared__ int se0;
    __shared__ int sAdj[SADJ_CAP];
    int t = threadIdx.x;
    int b = blockIdx.x;

    {
        int v = (t < ncb) ? min(bcount[t], BCAP) : 0;
        int lane = t & 63, w = t >> 6;
        int inc = v;
        for (int off = 1; off < 64; off <<= 1) {
            int u = __shfl_up(inc, off, 64);
            if (lane >= off) inc += u;
        }
        if (lane == 63) wsum4[w] = inc;
        __syncthreads();
        int wof = 0;
        for (int iw = 0; iw < w; ++iw) wof += wsum4[iw];
        int ex = wof + inc - v;
        if (t == b) se0 = ex;
        if (b == 0 && t == 0)
            rowptr[N] = wsum4[0] + wsum4[1] + wsum4[2] + wsum4[3];
    }
    __syncthreads();
    int e0 = se0;
    int len = min(bcount[b], BCAP);
    int nb = b << CB_SHIFT;
    const unsigned* slab = ebuf + (size_t)b * BCAP;

    cnt[2 * t] = 0; cnt[2 * t + 1] = 0;
    __syncthreads();
    for (int i = t; i < len; i += 256) {
        unsigned p = slab[i];
        atomicAdd(&cnt[p & (CB_NODES - 1)], 1);
    }
    __syncthreads();

    int c0 = cnt[2 * t], c1 = cnt[2 * t + 1];
    int s = c0 + c1;
    int lane = t & 63, wv = t >> 6;
    int inc = s;
    for (int off = 1; off < 64; off <<= 1) {
        int u = __shfl_up(inc, off, 64);
        if (lane >= off) inc += u;
    }
    if (lane == 63) wpart[wv] = inc;
    __syncthreads();
    int wof = 0;
    for (int w = 0; w < wv; ++w) wof += wpart[w];
    int ex = wof + inc - s;
    cur[2 * t] = ex; cur[2 * t + 1] = ex + c0;
    {
        int g = nb + 2 * t;
        if (g < N)     rowptr[g]     = e0 + ex;
        if (g + 1 < N) rowptr[g + 1] = e0 + ex + c0;
    }
    __syncthreads();

    int big = (len > SADJ_CAP);
    for (int i = t; i < len; i += 256) {
        unsigned p = slab[i];
        int dl = (int)(p & (CB_NODES - 1));
        int src = (int)(p >> CB_SHIFT);
        int pos = atomicAdd(&cur[dl], 1);
        if (big) adj[e0 + pos] = src;
        else     sAdj[pos] = src;
    }
    __syncthreads();
    if (!big) {
        for (int i = t; i < len; i += 256) adj[e0 + i] = sAdj[i];
    }
}

extern "C" void kernel_launch(void* const* d_in, const int* in_sizes, int n_in,
                              void* d_out, int out_size, void* d_ws, size_t ws_size,
                              hipStream_t stream) {
    const float* x    = (const float*)d_in[0];
    const void*  ei   = d_in[1];
    const float* Wl1  = (const float*)d_in[2];
    const float* bl1  = (const float*)d_in[3];
    const float* Wr1  = (const float*)d_in[4];
    const float* Wl2  = (const float*)d_in[5];
    const float* bl2  = (const float*)d_in[6];
    const float* Wr2  = (const float*)d_in[7];
    const float* Wl3  = (const float*)d_in[8];
    const float* bl3  = (const float*)d_in[9];
    const float* Wr3  = (const float*)d_in[10];
    const float* Wout = (const float*)d_in[11];
    const float* bout = (const float*)d_in[12];
    float* out = (float*)d_out;

    int       N = in_sizes[0] / D;
    long long E = (long long)in_sizes[1] / 2;
    int ncb = (N + CB_NODES - 1) >> CB_SHIFT;   // <= 256 for N <= 131072
    long long U = (long long)N * D / 8;         // float8 convert units

    // workspace layout
    char* ws = (char*)d_ws;
    size_t off = 256;
    int* bcursor = (int*)(ws + off); off += 1024;   // 256 ints
    int* rowptr = (int*)(ws + off); off += (((size_t)(N + 1) * 4 + 255) / 256) * 256;
    int* adj    = (int*)(ws + off); off += (((size_t)E * 4 + 255) / 256) * 256;
    unsigned* ebuf = (unsigned*)(ws + off); off += (size_t)ncb * BCAP * 4;
    _Float16* x16 = (_Float16*)(ws + off); off += (size_t)N * D * 2;
    _Float16* hA  = (_Float16*)(ws + off); off += (size_t)N * D * 2;
    _Float16* hB  = (_Float16*)(ws + off); off += (size_t)N * D * 2;
    _Float16* W16 = (_Float16*)(ws + off); off += 6 * 4096 * 2;

    int sgrid = (int)((E + CHUNK - 1) / CHUNK);
    int ggrid = (N + TILE - 1) / TILE;

    hipMemsetAsync(bcursor, 0, 1024, stream);

    // K1: CSR scatter runs concurrently with fp16 conversion of x and weights
    scatter_conv_kernel<<<sgrid + CGRID, 256, 0, stream>>>(
        ei, E, bcursor, ebuf, ncb, sgrid,
        x, x16, U, Wl1, Wr1, Wl2, Wr2, Wl3, Wr3, W16);
    finefill_kernel<<<ncb, 256, 0, stream>>>(ebuf, bcursor, rowptr, adj, N, ncb);
    // ---- layer 1 (fused agg+gemm) ----
    agg_gemm_kernel<<<ggrid, 256, 0, stream>>>(x16, rowptr, adj, W16, bl1, hA,
                                               Wout, bout, out, N, 0);
    // ---- layer 2 ----
    agg_gemm_kernel<<<ggrid, 256, 0, stream>>>(hA, rowptr, adj, W16 + 2 * 4096, bl2, hB,
                                               Wout, bout, out, N, 0);
    // ---- layer 3 + fused head (h4 never materialized) ----
    agg_gemm_kernel<<<ggrid, 256, 0, stream>>>(hB, rowptr, adj, W16 + 4 * 4096, bl3, hA,
                                               Wout, bout, out, N, 1);
}